// Round 6
// baseline (5352.237 us; speedup 1.0000x reference)
//
#include <hip/hip_runtime.h>

#define TDIM 512
#define BDIM 256
#define IDIM 64
#define HDIM 512

typedef short bf16x8 __attribute__((ext_vector_type(8)));
typedef float f32x4  __attribute__((ext_vector_type(4)));

__device__ __forceinline__ unsigned short f2bf(float f) {
  union { float f; unsigned u; } v; v.f = f;
  return (unsigned short)((v.u + 0x7fffu + ((v.u >> 16) & 1u)) >> 16);
}

__device__ __forceinline__ bf16x8 load8f_bf16(const float* p) {
  float4 a = *(const float4*)p;
  float4 b = *(const float4*)(p + 4);
  bf16x8 r;
  r[0] = (short)f2bf(a.x); r[1] = (short)f2bf(a.y);
  r[2] = (short)f2bf(a.z); r[3] = (short)f2bf(a.w);
  r[4] = (short)f2bf(b.x); r[5] = (short)f2bf(b.y);
  r[6] = (short)f2bf(b.z); r[7] = (short)f2bf(b.w);
  return r;
}

// device-coherent 16B read of 8 bf16 (sc0 sc1: bypass stale L1/L2, served by MALL)
__device__ __forceinline__ bf16x8 load_h16(const unsigned short* p) {
  union { unsigned long long u[2]; bf16x8 v; } r;
  r.u[0] = __hip_atomic_load((const unsigned long long*)p,
                             __ATOMIC_RELAXED, __HIP_MEMORY_SCOPE_AGENT);
  r.u[1] = __hip_atomic_load((const unsigned long long*)(p + 4),
                             __ATOMIC_RELAXED, __HIP_MEMORY_SCOPE_AGENT);
  return r.v;
}

__device__ __forceinline__ float sigm(float x)   { return 1.0f / (1.0f + __expf(-x)); }
__device__ __forceinline__ float tanh_f(float x) { return 2.0f / (1.0f + __expf(-2.0f * x)) - 1.0f; }

// poll a per-lane precomputed flag word until >= tgt (all 64 lanes agree)
__device__ __forceinline__ void wait_flags(const int* p, int tgt) {
  while (true) {
    int v = __hip_atomic_load(p, __ATOMIC_RELAXED, __HIP_MEMORY_SCOPE_AGENT);
    if (__all(v >= tgt)) break;
    __builtin_amdgcn_s_sleep(1);
  }
  asm volatile("" ::: "memory");   // keep h loads below the spin
}

// Persistent 2-layer LSTM, merged-round schedule + per-wave flags.
// 256 blocks x 256 threads, 1 block/CU. Block (bi=bid&7, hj=bid>>3):
// batch rows [bi*32,+32), hidden cols [hj*16,+16).
// Round t (0..512): layer0(t) [x[t], h0[t-1]] AND layer1(t-1) [h0[t-1], h1[t-2]].
// Flags: fw[bi][hj][wave] monotone round counters. Wave w of a consumer block
// waits only on the 8 producer blocks of its chunks (ch = w+4s), all 4 waves each
// (producers' rows are wave-split). Union over 4 waves = all 32 blocks => the
// mid-round __syncthreads preserves the R5 WAR invariant on parity buffers.
// Tail is barrier-free: each wave drains its own h stores then posts its word.
__global__ __launch_bounds__(256, 1)
void lstm_persist(const float* __restrict__ x,
                  const float* __restrict__ Wih0, const float* __restrict__ Whh0,
                  const float* __restrict__ bih0, const float* __restrict__ bhh0,
                  const float* __restrict__ Wih1, const float* __restrict__ Whh1,
                  const float* __restrict__ bih1, const float* __restrict__ bhh1,
                  unsigned short* __restrict__ h0b, unsigned short* __restrict__ h1b,
                  float* __restrict__ h1f, int* __restrict__ flags)
{
  const int tid  = threadIdx.x;
  const int w    = tid >> 6;          // wave 0..3
  const int lane = tid & 63;
  const int lrow = lane & 15;         // m/n index within fragment
  const int lk8  = (lane >> 4) << 3;  // k offset within 32-chunk
  const int bid  = blockIdx.x;
  const int bi   = bid & 7;           // batch group
  const int hj   = bid >> 3;          // col block 0..31

  int* fw = flags + bi * 128;         // [32 blocks][4 waves] round counters

  // per-lane poll pointer: lane l (l&31) -> producer pi=(l&31)>>2, wave w'=l&3
  // producer block hj' = 2*(w + 4*(pi>>1)) + (pi&1)
  const int pl  = lane & 31;
  const int pi  = pl >> 2;
  const int hjp = 2 * (w + 4 * (pi >> 1)) + (pi & 1);
  const int* pollp = fw + hjp * 4 + (pl & 3);
  int* postp = fw + hj * 4 + w;       // this wave's flag word

  __shared__ float part0[4 * 64 * 36];  // layer0 partials [wave][gatecol][row pad36]
  __shared__ float part1[4 * 64 * 36];  // layer1 partials

  // ---------------- weights -> registers (bf16 fragments), once ----------------
  bf16x8 bwx[4];        // W_ih0, x chunk (w<2 only)
  bf16x8 bw0h[4][4];    // W_hh0
  bf16x8 bw1a[4][4];    // W_ih1 (input = h0[t-1])
  bf16x8 bw1b[4][4];    // W_hh1 (input = h1[t-2])
  #pragma unroll
  for (int g = 0; g < 4; ++g) {
    int j = g * 512 + hj * 16 + lrow;
    if (w < 2) bwx[g] = load8f_bf16(Wih0 + (size_t)j * 64 + (w * 32 + lk8));
    else       { bf16x8 z = {0,0,0,0,0,0,0,0}; bwx[g] = z; }
    #pragma unroll
    for (int s = 0; s < 4; ++s) {
      int ch = w + 4 * s;
      bw0h[s][g] = load8f_bf16(Whh0 + (size_t)j * 512 + (ch * 32 + lk8));
      bw1a[s][g] = load8f_bf16(Wih1 + (size_t)j * 512 + (ch * 32 + lk8));
      bw1b[s][g] = load8f_bf16(Whh1 + (size_t)j * 512 + (ch * 32 + lk8));
    }
  }

  // ---------------- epilogue mapping: thread = (row r, col-pair hp) ----------------
  const int hp  = tid & 7;            // col pair 0..7
  const int r   = tid >> 3;           // batch row within tile 0..31
  const int jc0 = hj * 16 + 2 * hp;   // even global hidden col
  const int grow = bi * 32 + r;       // global batch row
  float bia0[2][4], bia1[2][4];
  #pragma unroll
  for (int cc = 0; cc < 2; ++cc)
    #pragma unroll
    for (int g = 0; g < 4; ++g) {
      bia0[cc][g] = bih0[g * 512 + jc0 + cc] + bhh0[g * 512 + jc0 + cc];
      bia1[cc][g] = bih1[g * 512 + jc0 + cc] + bhh1[g * 512 + jc0 + cc];
    }

  float c0s[2] = {0.f, 0.f}, c1s[2] = {0.f, 0.f};

  const size_t HB = (size_t)BDIM * HDIM;
  const int r0w = ((lane >> 4) << 2);

  #pragma unroll 1
  for (int t = 0; t <= TDIM; ++t) {
    f32x4 acc0[2][4], acc1[2][4];
    #pragma unroll
    for (int m = 0; m < 2; ++m)
      #pragma unroll
      for (int g = 0; g < 4; ++g) {
        f32x4 z = {0.f,0.f,0.f,0.f}; acc0[m][g] = z; acc1[m][g] = z;
      }

    // x chunk: no recurrent dependency, before the wait
    if (t < TDIM && w < 2) {
      bf16x8 a[2];
      #pragma unroll
      for (int m = 0; m < 2; ++m)
        a[m] = load8f_bf16(x + ((size_t)(bi * 32 + m * 16 + lrow) * TDIM + t) * IDIM + (w * 32 + lk8));
      #pragma unroll
      for (int m = 0; m < 2; ++m)
        #pragma unroll
        for (int g = 0; g < 4; ++g)
          acc0[m][g] = __builtin_amdgcn_mfma_f32_16x16x32_bf16(a[m], bwx[g], acc0[m][g], 0, 0, 0);
    }

    wait_flags(pollp, t);             // this wave's 8 producers finished round t-1

    // h0[t-1] at parity (t+1)&1 ; h1[t-2] at parity t&1
    const unsigned short* h0p = h0b + (size_t)((t + 1) & 1) * HB;
    const unsigned short* h1p = h1b + (size_t)(t & 1) * HB;

    // issue all h loads (pipelined MALL round trips)
    bf16x8 ah0[4][2], ah1[4][2];
    #pragma unroll
    for (int s = 0; s < 4; ++s) {
      int ch = w + 4 * s;
      #pragma unroll
      for (int m = 0; m < 2; ++m) {
        size_t row = (size_t)(bi * 32 + m * 16 + lrow) * HDIM;
        ah0[s][m] = load_h16(h0p + row + (ch * 32 + lk8));
        ah1[s][m] = load_h16(h1p + row + (ch * 32 + lk8));
      }
    }

    // layer0 recurrent GEMM (h0[t-1] x W_hh0)
    if (t < TDIM) {
      #pragma unroll
      for (int s = 0; s < 4; ++s)
        #pragma unroll
        for (int m = 0; m < 2; ++m)
          #pragma unroll
          for (int g = 0; g < 4; ++g)
            acc0[m][g] = __builtin_amdgcn_mfma_f32_16x16x32_bf16(ah0[s][m], bw0h[s][g], acc0[m][g], 0, 0, 0);
    }
    // layer1 GEMM (h0[t-1] x W_ih1 + h1[t-2] x W_hh1) — ah0 fragments shared
    if (t >= 1) {
      #pragma unroll
      for (int s = 0; s < 4; ++s)
        #pragma unroll
        for (int m = 0; m < 2; ++m)
          #pragma unroll
          for (int g = 0; g < 4; ++g) {
            acc1[m][g] = __builtin_amdgcn_mfma_f32_16x16x32_bf16(ah0[s][m], bw1a[s][g], acc1[m][g], 0, 0, 0);
            acc1[m][g] = __builtin_amdgcn_mfma_f32_16x16x32_bf16(ah1[s][m], bw1b[s][g], acc1[m][g], 0, 0, 0);
          }
    }

    __syncthreads();   // guard: prev round's epilogue LDS reads complete in ALL waves

    if (t < TDIM) {
      #pragma unroll
      for (int m = 0; m < 2; ++m)
        #pragma unroll
        for (int g = 0; g < 4; ++g)
          *(f32x4*)&part0[(w * 64 + g * 16 + lrow) * 36 + m * 16 + r0w] = acc0[m][g];
    }
    if (t >= 1) {
      #pragma unroll
      for (int m = 0; m < 2; ++m)
        #pragma unroll
        for (int g = 0; g < 4; ++g)
          *(f32x4*)&part1[(w * 64 + g * 16 + lrow) * 36 + m * 16 + r0w] = acc1[m][g];
    }
    __syncthreads();   // partials visible to all waves

    // -------- epilogue layer0: h0[t] -> parity t&1 --------
    if (t < TDIM) {
      unsigned short* h0w = h0b + (size_t)(t & 1) * HB;
      float hv[2];
      #pragma unroll
      for (int cc = 0; cc < 2; ++cc) {
        int hc = 2 * hp + cc;
        float gv[4];
        #pragma unroll
        for (int g = 0; g < 4; ++g) {
          float sum = bia0[cc][g];
          #pragma unroll
          for (int w4 = 0; w4 < 4; ++w4)
            sum += part0[(w4 * 64 + g * 16 + hc) * 36 + r];
          gv[g] = sum;
        }
        float ig = sigm(gv[0]), fg = sigm(gv[1]), gg = tanh_f(gv[2]), og = sigm(gv[3]);
        c0s[cc] = fg * c0s[cc] + ig * gg;
        hv[cc] = og * tanh_f(c0s[cc]);
      }
      unsigned packed = (unsigned)f2bf(hv[0]) | ((unsigned)f2bf(hv[1]) << 16);
      __hip_atomic_store((unsigned*)(h0w + (size_t)grow * HDIM + jc0), packed,
                         __ATOMIC_RELAXED, __HIP_MEMORY_SCOPE_AGENT);
    }
    // -------- epilogue layer1: h1[t-1] -> parity (t+1)&1 --------
    if (t >= 1) {
      unsigned short* h1w = h1b + (size_t)((t + 1) & 1) * HB;
      float hv[2];
      #pragma unroll
      for (int cc = 0; cc < 2; ++cc) {
        int hc = 2 * hp + cc;
        float gv[4];
        #pragma unroll
        for (int g = 0; g < 4; ++g) {
          float sum = bia1[cc][g];
          #pragma unroll
          for (int w4 = 0; w4 < 4; ++w4)
            sum += part1[(w4 * 64 + g * 16 + hc) * 36 + r];
          gv[g] = sum;
        }
        float ig = sigm(gv[0]), fg = sigm(gv[1]), gg = tanh_f(gv[2]), og = sigm(gv[3]);
        c1s[cc] = fg * c1s[cc] + ig * gg;
        hv[cc] = og * tanh_f(c1s[cc]);
      }
      unsigned packed = (unsigned)f2bf(hv[0]) | ((unsigned)f2bf(hv[1]) << 16);
      __hip_atomic_store((unsigned*)(h1w + (size_t)grow * HDIM + jc0), packed,
                         __ATOMIC_RELAXED, __HIP_MEMORY_SCOPE_AGENT);
      if (t == TDIM) {
        float2 o; o.x = hv[0]; o.y = hv[1];
        *(float2*)(h1f + (size_t)grow * HDIM + jc0) = o;
      }
    }

    // -------- barrier-free tail: per-wave drain + per-wave flag post --------
    asm volatile("s_waitcnt vmcnt(0)" ::: "memory");  // this wave's h stores visible
    if ((tid & 63) == 0)
      __hip_atomic_store(postp, t + 1, __ATOMIC_RELAXED, __HIP_MEMORY_SCOPE_AGENT);
  }
}

// out[b] = h1f[b,:] . Wlin + blin ; out[256] = mean((out - y)^2)
__global__ void head_k(const float* __restrict__ h1f, const float* __restrict__ Wlin,
                       const float* __restrict__ blin, const float* __restrict__ y,
                       float* __restrict__ dout)
{
  __shared__ float red[256];
  int b = threadIdx.x;
  const float4* hp = (const float4*)(h1f + (size_t)b * HDIM);
  const float4* wp = (const float4*)Wlin;
  float acc = 0.f;
  #pragma unroll 8
  for (int i = 0; i < HDIM / 4; ++i) {
    float4 h4 = hp[i]; float4 w4 = wp[i];
    acc += h4.x * w4.x + h4.y * w4.y + h4.z * w4.z + h4.w * w4.w;
  }
  float o = acc + blin[0];
  dout[b] = o;
  float d = o - y[b];
  red[b] = d * d;
  __syncthreads();
  for (int off = 128; off > 0; off >>= 1) {
    if (b < off) red[b] += red[b + off];
    __syncthreads();
  }
  if (b == 0) dout[256] = red[0] * (1.0f / 256.0f);
}

extern "C" void kernel_launch(void* const* d_in, const int* in_sizes, int n_in,
                              void* d_out, int out_size, void* d_ws, size_t ws_size,
                              hipStream_t stream)
{
  const float* x    = (const float*)d_in[0];
  const float* y    = (const float*)d_in[1];
  const float* Wih0 = (const float*)d_in[2];
  const float* Whh0 = (const float*)d_in[3];
  const float* bih0 = (const float*)d_in[4];
  const float* bhh0 = (const float*)d_in[5];
  const float* Wih1 = (const float*)d_in[6];
  const float* Whh1 = (const float*)d_in[7];
  const float* bih1 = (const float*)d_in[8];
  const float* bhh1 = (const float*)d_in[9];
  const float* Wlin = (const float*)d_in[10];
  const float* blin = (const float*)d_in[11];

  char* ws = (char*)d_ws;
  unsigned short* h0b = (unsigned short*)ws;             // 2*256*512*2 = 524,288 B
  unsigned short* h1b = (unsigned short*)(ws + 524288);  // 524,288 B
  int*   flags = (int*)(ws + 1048576);                   // 8 groups * 128 words = 4 KB
  float* h1f   = (float*)(ws + 1048576 + 4096);          // 256*512*4 = 524,288 B

  // zero h buffers (h[-1]=h[-2]=0) + flag words every call (graph-replay safe)
  hipMemsetAsync(d_ws, 0, 1048576 + 4096, stream);

  hipLaunchKernelGGL(lstm_persist, dim3(256), dim3(256), 0, stream,
                     x, Wih0, Whh0, bih0, bhh0, Wih1, Whh1, bih1, bhh1,
                     h0b, h1b, h1f, flags);
  hipLaunchKernelGGL(head_k, dim3(1), dim3(256), 0, stream,
                     h1f, Wlin, blin, y, (float*)d_out);
}

// Round 7
// 3631.310 us; speedup vs baseline: 1.4739x; 1.4739x over previous
//
#include <hip/hip_runtime.h>

#define TDIM 512
#define BDIM 256
#define IDIM 64
#define HDIM 512

typedef short bf16x8 __attribute__((ext_vector_type(8)));
typedef float f32x4  __attribute__((ext_vector_type(4)));

__device__ __forceinline__ unsigned short f2bf(float f) {
  union { float f; unsigned u; } v; v.f = f;
  return (unsigned short)((v.u + 0x7fffu + ((v.u >> 16) & 1u)) >> 16);
}

__device__ __forceinline__ bf16x8 load8f_bf16(const float* p) {
  float4 a = *(const float4*)p;
  float4 b = *(const float4*)(p + 4);
  bf16x8 r;
  r[0] = (short)f2bf(a.x); r[1] = (short)f2bf(a.y);
  r[2] = (short)f2bf(a.z); r[3] = (short)f2bf(a.w);
  r[4] = (short)f2bf(b.x); r[5] = (short)f2bf(b.y);
  r[6] = (short)f2bf(b.z); r[7] = (short)f2bf(b.w);
  return r;
}

// device-coherent 16B read of 8 bf16 (sc0 sc1: bypass stale L1/L2, served by MALL)
__device__ __forceinline__ bf16x8 load_h16(const unsigned short* p) {
  union { unsigned long long u[2]; bf16x8 v; } r;
  r.u[0] = __hip_atomic_load((const unsigned long long*)p,
                             __ATOMIC_RELAXED, __HIP_MEMORY_SCOPE_AGENT);
  r.u[1] = __hip_atomic_load((const unsigned long long*)(p + 4),
                             __ATOMIC_RELAXED, __HIP_MEMORY_SCOPE_AGENT);
  return r.v;
}

__device__ __forceinline__ float sigm(float x)   { return 1.0f / (1.0f + __expf(-x)); }
__device__ __forceinline__ float tanh_f(float x) { return 2.0f / (1.0f + __expf(-2.0f * x)) - 1.0f; }

// LOW-PRESSURE wait: ONLY wave 0 polls (lanes 0..31, one sc1 load / 512cy);
// waves 1..3 park at the barrier. ~16x less poll traffic than R5 on the hot
// flag cacheline -> producer flag-stores stop queueing behind the poll storm.
__device__ __forceinline__ void wait32_w0(const int* base, int tgt) {
  if ((threadIdx.x >> 6) == 0) {
    const int* p = base + (threadIdx.x & 31);
    while (true) {
      int v = __hip_atomic_load(p, __ATOMIC_RELAXED, __HIP_MEMORY_SCOPE_AGENT);
      if (__all(v >= tgt)) break;
      __builtin_amdgcn_s_sleep(8);
    }
  }
  __syncthreads();
  asm volatile("" ::: "memory");   // keep h loads below the wait
}

// Persistent 2-layer LSTM, merged-round schedule (R5 structure).
// 256 blocks x 256 threads, 1 block/CU. Block (bi=bid&7, hj=bid>>3):
// batch rows [bi*32,+32), hidden cols [hj*16,+16).
// Round t (t = 0..512): compute layer0(t) [needs x[t], h0[t-1]] AND
// layer1(t-1) [needs h0[t-1], h1[t-2]] -> ONE wait + ONE flag post per round.
// h0[2][256][512]: h0[t] at parity t&1.  h1[2][256][512]: h1[t] at parity t&1.
// Sync: per-block monotone words (words[bi][32]); all cross-block data via
// MALL-coherent (sc0 sc1) relaxed-atomic accesses. Proven R2/R5 protocol.
__global__ __launch_bounds__(256, 1)
void lstm_persist(const float* __restrict__ x,
                  const float* __restrict__ Wih0, const float* __restrict__ Whh0,
                  const float* __restrict__ bih0, const float* __restrict__ bhh0,
                  const float* __restrict__ Wih1, const float* __restrict__ Whh1,
                  const float* __restrict__ bih1, const float* __restrict__ bhh1,
                  unsigned short* __restrict__ h0b, unsigned short* __restrict__ h1b,
                  float* __restrict__ h1f, int* __restrict__ flags)
{
  const int tid  = threadIdx.x;
  const int w    = tid >> 6;          // wave 0..3
  const int lane = tid & 63;
  const int lrow = lane & 15;         // m/n index within fragment
  const int lk8  = (lane >> 4) << 3;  // k offset within 32-chunk
  const int bid  = blockIdx.x;
  const int bi   = bid & 7;           // batch group
  const int hj   = bid >> 3;          // col block 0..31

  int* words = flags + bi * 32;       // [32] per-col-block round counter

  __shared__ float part0[4 * 64 * 36];  // layer0 partials [wave][gatecol][row pad36]
  __shared__ float part1[4 * 64 * 36];  // layer1 partials

  // ---------------- weights -> registers (bf16 fragments), once ----------------
  // K-chunk ownership: wave w owns h-chunks ch = w + 4*s (s=0..3); x-chunk w (w<2).
  bf16x8 bwx[4];        // W_ih0, x chunk (w<2 only)
  bf16x8 bw0h[4][4];    // W_hh0
  bf16x8 bw1a[4][4];    // W_ih1 (input = h0[t-1])
  bf16x8 bw1b[4][4];    // W_hh1 (input = h1[t-2])
  #pragma unroll
  for (int g = 0; g < 4; ++g) {
    int j = g * 512 + hj * 16 + lrow;
    if (w < 2) bwx[g] = load8f_bf16(Wih0 + (size_t)j * 64 + (w * 32 + lk8));
    else       { bf16x8 z = {0,0,0,0,0,0,0,0}; bwx[g] = z; }
    #pragma unroll
    for (int s = 0; s < 4; ++s) {
      int ch = w + 4 * s;
      bw0h[s][g] = load8f_bf16(Whh0 + (size_t)j * 512 + (ch * 32 + lk8));
      bw1a[s][g] = load8f_bf16(Wih1 + (size_t)j * 512 + (ch * 32 + lk8));
      bw1b[s][g] = load8f_bf16(Whh1 + (size_t)j * 512 + (ch * 32 + lk8));
    }
  }

  // ---------------- epilogue mapping: thread = (row r, col-pair hp) ----------------
  const int hp  = tid & 7;            // col pair 0..7
  const int r   = tid >> 3;           // batch row within tile 0..31
  const int jc0 = hj * 16 + 2 * hp;   // even global hidden col
  const int grow = bi * 32 + r;       // global batch row
  float bia0[2][4], bia1[2][4];
  #pragma unroll
  for (int cc = 0; cc < 2; ++cc)
    #pragma unroll
    for (int g = 0; g < 4; ++g) {
      bia0[cc][g] = bih0[g * 512 + jc0 + cc] + bhh0[g * 512 + jc0 + cc];
      bia1[cc][g] = bih1[g * 512 + jc0 + cc] + bhh1[g * 512 + jc0 + cc];
    }

  float c0s[2] = {0.f, 0.f}, c1s[2] = {0.f, 0.f};

  const size_t HB = (size_t)BDIM * HDIM;
  const int r0w = ((lane >> 4) << 2);

  #pragma unroll 1
  for (int t = 0; t <= TDIM; ++t) {
    f32x4 acc0[2][4], acc1[2][4];
    #pragma unroll
    for (int m = 0; m < 2; ++m)
      #pragma unroll
      for (int g = 0; g < 4; ++g) {
        f32x4 z = {0.f,0.f,0.f,0.f}; acc0[m][g] = z; acc1[m][g] = z;
      }

    // x chunk: no recurrent dependency, before the wait
    if (t < TDIM && w < 2) {
      bf16x8 a[2];
      #pragma unroll
      for (int m = 0; m < 2; ++m)
        a[m] = load8f_bf16(x + ((size_t)(bi * 32 + m * 16 + lrow) * TDIM + t) * IDIM + (w * 32 + lk8));
      #pragma unroll
      for (int m = 0; m < 2; ++m)
        #pragma unroll
        for (int g = 0; g < 4; ++g)
          acc0[m][g] = __builtin_amdgcn_mfma_f32_16x16x32_bf16(a[m], bwx[g], acc0[m][g], 0, 0, 0);
    }

    wait32_w0(words, t);              // all group blocks completed round t-1

    // h0[t-1] at parity (t-1)&1 = (t+1)&1 ; h1[t-2] at parity (t-2)&1 = t&1
    const unsigned short* h0p = h0b + (size_t)((t + 1) & 1) * HB;
    const unsigned short* h1p = h1b + (size_t)(t & 1) * HB;

    // issue ALL shared h loads first (pipelined MALL round trips)
    bf16x8 ah0[4][2], ah1[4][2];
    #pragma unroll
    for (int s = 0; s < 4; ++s) {
      int ch = w + 4 * s;
      #pragma unroll
      for (int m = 0; m < 2; ++m) {
        size_t row = (size_t)(bi * 32 + m * 16 + lrow) * HDIM;
        ah0[s][m] = load_h16(h0p + row + (ch * 32 + lk8));
        ah1[s][m] = load_h16(h1p + row + (ch * 32 + lk8));
      }
    }

    // layer0 recurrent GEMM (h0[t-1] x W_hh0)
    if (t < TDIM) {
      #pragma unroll
      for (int s = 0; s < 4; ++s)
        #pragma unroll
        for (int m = 0; m < 2; ++m)
          #pragma unroll
          for (int g = 0; g < 4; ++g)
            acc0[m][g] = __builtin_amdgcn_mfma_f32_16x16x32_bf16(ah0[s][m], bw0h[s][g], acc0[m][g], 0, 0, 0);
    }
    // layer1 GEMM (h0[t-1] x W_ih1  +  h1[t-2] x W_hh1) — ah0 fragments shared!
    if (t >= 1) {
      #pragma unroll
      for (int s = 0; s < 4; ++s)
        #pragma unroll
        for (int m = 0; m < 2; ++m)
          #pragma unroll
          for (int g = 0; g < 4; ++g) {
            acc1[m][g] = __builtin_amdgcn_mfma_f32_16x16x32_bf16(ah0[s][m], bw1a[s][g], acc1[m][g], 0, 0, 0);
            acc1[m][g] = __builtin_amdgcn_mfma_f32_16x16x32_bf16(ah1[s][m], bw1b[s][g], acc1[m][g], 0, 0, 0);
          }
    }

    if (t < TDIM) {
      #pragma unroll
      for (int m = 0; m < 2; ++m)
        #pragma unroll
        for (int g = 0; g < 4; ++g)
          *(f32x4*)&part0[(w * 64 + g * 16 + lrow) * 36 + m * 16 + r0w] = acc0[m][g];
    }
    if (t >= 1) {
      #pragma unroll
      for (int m = 0; m < 2; ++m)
        #pragma unroll
        for (int g = 0; g < 4; ++g)
          *(f32x4*)&part1[(w * 64 + g * 16 + lrow) * 36 + m * 16 + r0w] = acc1[m][g];
    }
    __syncthreads();

    // -------- epilogue layer0: h0[t] -> parity t&1 --------
    if (t < TDIM) {
      unsigned short* h0w = h0b + (size_t)(t & 1) * HB;
      float hv[2];
      #pragma unroll
      for (int cc = 0; cc < 2; ++cc) {
        int hc = 2 * hp + cc;
        float gv[4];
        #pragma unroll
        for (int g = 0; g < 4; ++g) {
          float sum = bia0[cc][g];
          #pragma unroll
          for (int w4 = 0; w4 < 4; ++w4)
            sum += part0[(w4 * 64 + g * 16 + hc) * 36 + r];
          gv[g] = sum;
        }
        float ig = sigm(gv[0]), fg = sigm(gv[1]), gg = tanh_f(gv[2]), og = sigm(gv[3]);
        c0s[cc] = fg * c0s[cc] + ig * gg;
        hv[cc] = og * tanh_f(c0s[cc]);
      }
      unsigned packed = (unsigned)f2bf(hv[0]) | ((unsigned)f2bf(hv[1]) << 16);
      __hip_atomic_store((unsigned*)(h0w + (size_t)grow * HDIM + jc0), packed,
                         __ATOMIC_RELAXED, __HIP_MEMORY_SCOPE_AGENT);
    }
    // -------- epilogue layer1: h1[t-1] -> parity (t-1)&1 = (t+1)&1 --------
    if (t >= 1) {
      unsigned short* h1w = h1b + (size_t)((t + 1) & 1) * HB;
      float hv[2];
      #pragma unroll
      for (int cc = 0; cc < 2; ++cc) {
        int hc = 2 * hp + cc;
        float gv[4];
        #pragma unroll
        for (int g = 0; g < 4; ++g) {
          float sum = bia1[cc][g];
          #pragma unroll
          for (int w4 = 0; w4 < 4; ++w4)
            sum += part1[(w4 * 64 + g * 16 + hc) * 36 + r];
          gv[g] = sum;
        }
        float ig = sigm(gv[0]), fg = sigm(gv[1]), gg = tanh_f(gv[2]), og = sigm(gv[3]);
        c1s[cc] = fg * c1s[cc] + ig * gg;
        hv[cc] = og * tanh_f(c1s[cc]);
      }
      unsigned packed = (unsigned)f2bf(hv[0]) | ((unsigned)f2bf(hv[1]) << 16);
      __hip_atomic_store((unsigned*)(h1w + (size_t)grow * HDIM + jc0), packed,
                         __ATOMIC_RELAXED, __HIP_MEMORY_SCOPE_AGENT);
      if (t == TDIM) {
        float2 o; o.x = hv[0]; o.y = hv[1];
        *(float2*)(h1f + (size_t)grow * HDIM + jc0) = o;
      }
    }

    asm volatile("s_waitcnt vmcnt(0)" ::: "memory");  // h stores device-visible
    __syncthreads();                                  // all waves drained (+ LDS WAR)
    if (tid == 0)
      __hip_atomic_store(&words[hj], t + 1, __ATOMIC_RELAXED, __HIP_MEMORY_SCOPE_AGENT);
  }
}

// out[b] = h1f[b,:] . Wlin + blin ; out[256] = mean((out - y)^2)
__global__ void head_k(const float* __restrict__ h1f, const float* __restrict__ Wlin,
                       const float* __restrict__ blin, const float* __restrict__ y,
                       float* __restrict__ dout)
{
  __shared__ float red[256];
  int b = threadIdx.x;
  const float4* hp = (const float4*)(h1f + (size_t)b * HDIM);
  const float4* wp = (const float4*)Wlin;
  float acc = 0.f;
  #pragma unroll 8
  for (int i = 0; i < HDIM / 4; ++i) {
    float4 h4 = hp[i]; float4 w4 = wp[i];
    acc += h4.x * w4.x + h4.y * w4.y + h4.z * w4.z + h4.w * w4.w;
  }
  float o = acc + blin[0];
  dout[b] = o;
  float d = o - y[b];
  red[b] = d * d;
  __syncthreads();
  for (int off = 128; off > 0; off >>= 1) {
    if (b < off) red[b] += red[b + off];
    __syncthreads();
  }
  if (b == 0) dout[256] = red[0] * (1.0f / 256.0f);
}

extern "C" void kernel_launch(void* const* d_in, const int* in_sizes, int n_in,
                              void* d_out, int out_size, void* d_ws, size_t ws_size,
                              hipStream_t stream)
{
  const float* x    = (const float*)d_in[0];
  const float* y    = (const float*)d_in[1];
  const float* Wih0 = (const float*)d_in[2];
  const float* Whh0 = (const float*)d_in[3];
  const float* bih0 = (const float*)d_in[4];
  const float* bhh0 = (const float*)d_in[5];
  const float* Wih1 = (const float*)d_in[6];
  const float* Whh1 = (const float*)d_in[7];
  const float* bih1 = (const float*)d_in[8];
  const float* bhh1 = (const float*)d_in[9];
  const float* Wlin = (const float*)d_in[10];
  const float* blin = (const float*)d_in[11];

  char* ws = (char*)d_ws;
  unsigned short* h0b = (unsigned short*)ws;             // 2*256*512*2 = 524,288 B
  unsigned short* h1b = (unsigned short*)(ws + 524288);  // 524,288 B
  int*   flags = (int*)(ws + 1048576);                   // 8 groups * 32 words (4 KB pad)
  float* h1f   = (float*)(ws + 1048576 + 4096);          // 256*512*4 = 524,288 B

  // zero h buffers (h[-1]=h[-2]=0) + flag words every call (graph-replay safe)
  hipMemsetAsync(d_ws, 0, 1048576 + 4096, stream);

  hipLaunchKernelGGL(lstm_persist, dim3(256), dim3(256), 0, stream,
                     x, Wih0, Whh0, bih0, bhh0, Wih1, Whh1, bih1, bhh1,
                     h0b, h1b, h1f, flags);
  hipLaunchKernelGGL(head_k, dim3(1), dim3(256), 0, stream,
                     h1f, Wlin, blin, y, (float*)d_out);
}

// Round 8
// 3628.802 us; speedup vs baseline: 1.4749x; 1.0007x over previous
//
#include <hip/hip_runtime.h>

#define TDIM 512
#define BDIM 256
#define IDIM 64
#define HDIM 512

typedef short bf16x8 __attribute__((ext_vector_type(8)));
typedef float f32x4  __attribute__((ext_vector_type(4)));

__device__ __forceinline__ unsigned short f2bf(float f) {
  union { float f; unsigned u; } v; v.f = f;
  return (unsigned short)((v.u + 0x7fffu + ((v.u >> 16) & 1u)) >> 16);
}

__device__ __forceinline__ bf16x8 load8f_bf16(const float* p) {
  float4 a = *(const float4*)p;
  float4 b = *(const float4*)(p + 4);
  bf16x8 r;
  r[0] = (short)f2bf(a.x); r[1] = (short)f2bf(a.y);
  r[2] = (short)f2bf(a.z); r[3] = (short)f2bf(a.w);
  r[4] = (short)f2bf(b.x); r[5] = (short)f2bf(b.y);
  r[6] = (short)f2bf(b.z); r[7] = (short)f2bf(b.w);
  return r;
}

// device-coherent 16B read of 8 bf16 (sc0 sc1: bypass stale L1/L2, served by MALL)
__device__ __forceinline__ bf16x8 load_h16(const unsigned short* p) {
  union { unsigned long long u[2]; bf16x8 v; } r;
  r.u[0] = __hip_atomic_load((const unsigned long long*)p,
                             __ATOMIC_RELAXED, __HIP_MEMORY_SCOPE_AGENT);
  r.u[1] = __hip_atomic_load((const unsigned long long*)(p + 4),
                             __ATOMIC_RELAXED, __HIP_MEMORY_SCOPE_AGENT);
  return r.v;
}

__device__ __forceinline__ float sigm(float x)   { return 1.0f / (1.0f + __expf(-x)); }
__device__ __forceinline__ float tanh_f(float x) { return 2.0f / (1.0f + __expf(-2.0f * x)) - 1.0f; }

// LOW-PRESSURE wait: ONLY wave 0 polls (lanes 0..31, one sc1 load / 512cy);
// waves 1..3 park at the barrier. ~16x less poll traffic than R5 on the hot
// flag cacheline -> producer flag-stores stop queueing behind the poll storm.
__device__ __forceinline__ void wait32_w0(const int* base, int tgt) {
  if ((threadIdx.x >> 6) == 0) {
    const int* p = base + (threadIdx.x & 31);
    while (true) {
      int v = __hip_atomic_load(p, __ATOMIC_RELAXED, __HIP_MEMORY_SCOPE_AGENT);
      if (__all(v >= tgt)) break;
      __builtin_amdgcn_s_sleep(8);
    }
  }
  __syncthreads();
  asm volatile("" ::: "memory");   // keep h loads below the wait
}

// Persistent 2-layer LSTM, merged-round schedule (R5 structure).
// 256 blocks x 256 threads, 1 block/CU. Block (bi=bid&7, hj=bid>>3):
// batch rows [bi*32,+32), hidden cols [hj*16,+16).
// Round t (t = 0..512): compute layer0(t) [needs x[t], h0[t-1]] AND
// layer1(t-1) [needs h0[t-1], h1[t-2]] -> ONE wait + ONE flag post per round.
// h0[2][256][512]: h0[t] at parity t&1.  h1[2][256][512]: h1[t] at parity t&1.
// Sync: per-block monotone words (words[bi][32]); all cross-block data via
// MALL-coherent (sc0 sc1) relaxed-atomic accesses. Proven R2/R5 protocol.
__global__ __launch_bounds__(256, 1)
void lstm_persist(const float* __restrict__ x,
                  const float* __restrict__ Wih0, const float* __restrict__ Whh0,
                  const float* __restrict__ bih0, const float* __restrict__ bhh0,
                  const float* __restrict__ Wih1, const float* __restrict__ Whh1,
                  const float* __restrict__ bih1, const float* __restrict__ bhh1,
                  unsigned short* __restrict__ h0b, unsigned short* __restrict__ h1b,
                  float* __restrict__ h1f, int* __restrict__ flags)
{
  const int tid  = threadIdx.x;
  const int w    = tid >> 6;          // wave 0..3
  const int lane = tid & 63;
  const int lrow = lane & 15;         // m/n index within fragment
  const int lk8  = (lane >> 4) << 3;  // k offset within 32-chunk
  const int bid  = blockIdx.x;
  const int bi   = bid & 7;           // batch group
  const int hj   = bid >> 3;          // col block 0..31

  int* words = flags + bi * 32;       // [32] per-col-block round counter

  __shared__ float part0[4 * 64 * 36];  // layer0 partials [wave][gatecol][row pad36]
  __shared__ float part1[4 * 64 * 36];  // layer1 partials

  // ---------------- weights -> registers (bf16 fragments), once ----------------
  // K-chunk ownership: wave w owns h-chunks ch = w + 4*s (s=0..3); x-chunk w (w<2).
  bf16x8 bwx[4];        // W_ih0, x chunk (w<2 only)
  bf16x8 bw0h[4][4];    // W_hh0
  bf16x8 bw1a[4][4];    // W_ih1 (input = h0[t-1])
  bf16x8 bw1b[4][4];    // W_hh1 (input = h1[t-2])
  #pragma unroll
  for (int g = 0; g < 4; ++g) {
    int j = g * 512 + hj * 16 + lrow;
    if (w < 2) bwx[g] = load8f_bf16(Wih0 + (size_t)j * 64 + (w * 32 + lk8));
    else       { bf16x8 z = {0,0,0,0,0,0,0,0}; bwx[g] = z; }
    #pragma unroll
    for (int s = 0; s < 4; ++s) {
      int ch = w + 4 * s;
      bw0h[s][g] = load8f_bf16(Whh0 + (size_t)j * 512 + (ch * 32 + lk8));
      bw1a[s][g] = load8f_bf16(Wih1 + (size_t)j * 512 + (ch * 32 + lk8));
      bw1b[s][g] = load8f_bf16(Whh1 + (size_t)j * 512 + (ch * 32 + lk8));
    }
  }

  // ---------------- epilogue mapping: thread = (row r, col-pair hp) ----------------
  const int hp  = tid & 7;            // col pair 0..7
  const int r   = tid >> 3;           // batch row within tile 0..31
  const int jc0 = hj * 16 + 2 * hp;   // even global hidden col
  const int grow = bi * 32 + r;       // global batch row
  float bia0[2][4], bia1[2][4];
  #pragma unroll
  for (int cc = 0; cc < 2; ++cc)
    #pragma unroll
    for (int g = 0; g < 4; ++g) {
      bia0[cc][g] = bih0[g * 512 + jc0 + cc] + bhh0[g * 512 + jc0 + cc];
      bia1[cc][g] = bih1[g * 512 + jc0 + cc] + bhh1[g * 512 + jc0 + cc];
    }

  float c0s[2] = {0.f, 0.f}, c1s[2] = {0.f, 0.f};

  const size_t HB = (size_t)BDIM * HDIM;
  const int r0w = ((lane >> 4) << 2);

  #pragma unroll 1
  for (int t = 0; t <= TDIM; ++t) {
    f32x4 acc0[2][4], acc1[2][4];
    #pragma unroll
    for (int m = 0; m < 2; ++m)
      #pragma unroll
      for (int g = 0; g < 4; ++g) {
        f32x4 z = {0.f,0.f,0.f,0.f}; acc0[m][g] = z; acc1[m][g] = z;
      }

    // x chunk: no recurrent dependency, before the wait
    if (t < TDIM && w < 2) {
      bf16x8 a[2];
      #pragma unroll
      for (int m = 0; m < 2; ++m)
        a[m] = load8f_bf16(x + ((size_t)(bi * 32 + m * 16 + lrow) * TDIM + t) * IDIM + (w * 32 + lk8));
      #pragma unroll
      for (int m = 0; m < 2; ++m)
        #pragma unroll
        for (int g = 0; g < 4; ++g)
          acc0[m][g] = __builtin_amdgcn_mfma_f32_16x16x32_bf16(a[m], bwx[g], acc0[m][g], 0, 0, 0);
    }

    wait32_w0(words, t);              // all group blocks completed round t-1

    // h0[t-1] at parity (t-1)&1 = (t+1)&1 ; h1[t-2] at parity (t-2)&1 = t&1
    const unsigned short* h0p = h0b + (size_t)((t + 1) & 1) * HB;
    const unsigned short* h1p = h1b + (size_t)(t & 1) * HB;

    // issue ALL shared h loads first (pipelined MALL round trips)
    bf16x8 ah0[4][2], ah1[4][2];
    #pragma unroll
    for (int s = 0; s < 4; ++s) {
      int ch = w + 4 * s;
      #pragma unroll
      for (int m = 0; m < 2; ++m) {
        size_t row = (size_t)(bi * 32 + m * 16 + lrow) * HDIM;
        ah0[s][m] = load_h16(h0p + row + (ch * 32 + lk8));
        ah1[s][m] = load_h16(h1p + row + (ch * 32 + lk8));
      }
    }

    // layer0 recurrent GEMM (h0[t-1] x W_hh0)
    if (t < TDIM) {
      #pragma unroll
      for (int s = 0; s < 4; ++s)
        #pragma unroll
        for (int m = 0; m < 2; ++m)
          #pragma unroll
          for (int g = 0; g < 4; ++g)
            acc0[m][g] = __builtin_amdgcn_mfma_f32_16x16x32_bf16(ah0[s][m], bw0h[s][g], acc0[m][g], 0, 0, 0);
    }
    // layer1 GEMM (h0[t-1] x W_ih1  +  h1[t-2] x W_hh1) — ah0 fragments shared!
    if (t >= 1) {
      #pragma unroll
      for (int s = 0; s < 4; ++s)
        #pragma unroll
        for (int m = 0; m < 2; ++m)
          #pragma unroll
          for (int g = 0; g < 4; ++g) {
            acc1[m][g] = __builtin_amdgcn_mfma_f32_16x16x32_bf16(ah0[s][m], bw1a[s][g], acc1[m][g], 0, 0, 0);
            acc1[m][g] = __builtin_amdgcn_mfma_f32_16x16x32_bf16(ah1[s][m], bw1b[s][g], acc1[m][g], 0, 0, 0);
          }
    }

    if (t < TDIM) {
      #pragma unroll
      for (int m = 0; m < 2; ++m)
        #pragma unroll
        for (int g = 0; g < 4; ++g)
          *(f32x4*)&part0[(w * 64 + g * 16 + lrow) * 36 + m * 16 + r0w] = acc0[m][g];
    }
    if (t >= 1) {
      #pragma unroll
      for (int m = 0; m < 2; ++m)
        #pragma unroll
        for (int g = 0; g < 4; ++g)
          *(f32x4*)&part1[(w * 64 + g * 16 + lrow) * 36 + m * 16 + r0w] = acc1[m][g];
    }
    __syncthreads();

    // -------- epilogue layer0: h0[t] -> parity t&1 --------
    if (t < TDIM) {
      unsigned short* h0w = h0b + (size_t)(t & 1) * HB;
      float hv[2];
      #pragma unroll
      for (int cc = 0; cc < 2; ++cc) {
        int hc = 2 * hp + cc;
        float gv[4];
        #pragma unroll
        for (int g = 0; g < 4; ++g) {
          float sum = bia0[cc][g];
          #pragma unroll
          for (int w4 = 0; w4 < 4; ++w4)
            sum += part0[(w4 * 64 + g * 16 + hc) * 36 + r];
          gv[g] = sum;
        }
        float ig = sigm(gv[0]), fg = sigm(gv[1]), gg = tanh_f(gv[2]), og = sigm(gv[3]);
        c0s[cc] = fg * c0s[cc] + ig * gg;
        hv[cc] = og * tanh_f(c0s[cc]);
      }
      unsigned packed = (unsigned)f2bf(hv[0]) | ((unsigned)f2bf(hv[1]) << 16);
      __hip_atomic_store((unsigned*)(h0w + (size_t)grow * HDIM + jc0), packed,
                         __ATOMIC_RELAXED, __HIP_MEMORY_SCOPE_AGENT);
    }
    // -------- epilogue layer1: h1[t-1] -> parity (t-1)&1 = (t+1)&1 --------
    if (t >= 1) {
      unsigned short* h1w = h1b + (size_t)((t + 1) & 1) * HB;
      float hv[2];
      #pragma unroll
      for (int cc = 0; cc < 2; ++cc) {
        int hc = 2 * hp + cc;
        float gv[4];
        #pragma unroll
        for (int g = 0; g < 4; ++g) {
          float sum = bia1[cc][g];
          #pragma unroll
          for (int w4 = 0; w4 < 4; ++w4)
            sum += part1[(w4 * 64 + g * 16 + hc) * 36 + r];
          gv[g] = sum;
        }
        float ig = sigm(gv[0]), fg = sigm(gv[1]), gg = tanh_f(gv[2]), og = sigm(gv[3]);
        c1s[cc] = fg * c1s[cc] + ig * gg;
        hv[cc] = og * tanh_f(c1s[cc]);
      }
      unsigned packed = (unsigned)f2bf(hv[0]) | ((unsigned)f2bf(hv[1]) << 16);
      __hip_atomic_store((unsigned*)(h1w + (size_t)grow * HDIM + jc0), packed,
                         __ATOMIC_RELAXED, __HIP_MEMORY_SCOPE_AGENT);
      if (t == TDIM) {
        float2 o; o.x = hv[0]; o.y = hv[1];
        *(float2*)(h1f + (size_t)grow * HDIM + jc0) = o;
      }
    }

    asm volatile("s_waitcnt vmcnt(0)" ::: "memory");  // h stores device-visible
    __syncthreads();                                  // all waves drained (+ LDS WAR)
    if (tid == 0)
      __hip_atomic_store(&words[hj], t + 1, __ATOMIC_RELAXED, __HIP_MEMORY_SCOPE_AGENT);
  }
}

// out[b] = h1f[b,:] . Wlin + blin ; out[256] = mean((out - y)^2)
__global__ void head_k(const float* __restrict__ h1f, const float* __restrict__ Wlin,
                       const float* __restrict__ blin, const float* __restrict__ y,
                       float* __restrict__ dout)
{
  __shared__ float red[256];
  int b = threadIdx.x;
  const float4* hp = (const float4*)(h1f + (size_t)b * HDIM);
  const float4* wp = (const float4*)Wlin;
  float acc = 0.f;
  #pragma unroll 8
  for (int i = 0; i < HDIM / 4; ++i) {
    float4 h4 = hp[i]; float4 w4 = wp[i];
    acc += h4.x * w4.x + h4.y * w4.y + h4.z * w4.z + h4.w * w4.w;
  }
  float o = acc + blin[0];
  dout[b] = o;
  float d = o - y[b];
  red[b] = d * d;
  __syncthreads();
  for (int off = 128; off > 0; off >>= 1) {
    if (b < off) red[b] += red[b + off];
    __syncthreads();
  }
  if (b == 0) dout[256] = red[0] * (1.0f / 256.0f);
}

extern "C" void kernel_launch(void* const* d_in, const int* in_sizes, int n_in,
                              void* d_out, int out_size, void* d_ws, size_t ws_size,
                              hipStream_t stream)
{
  const float* x    = (const float*)d_in[0];
  const float* y    = (const float*)d_in[1];
  const float* Wih0 = (const float*)d_in[2];
  const float* Whh0 = (const float*)d_in[3];
  const float* bih0 = (const float*)d_in[4];
  const float* bhh0 = (const float*)d_in[5];
  const float* Wih1 = (const float*)d_in[6];
  const float* Whh1 = (const float*)d_in[7];
  const float* bih1 = (const float*)d_in[8];
  const float* bhh1 = (const float*)d_in[9];
  const float* Wlin = (const float*)d_in[10];
  const float* blin = (const float*)d_in[11];

  char* ws = (char*)d_ws;
  unsigned short* h0b = (unsigned short*)ws;             // 2*256*512*2 = 524,288 B
  unsigned short* h1b = (unsigned short*)(ws + 524288);  // 524,288 B
  int*   flags = (int*)(ws + 1048576);                   // 8 groups * 32 words (4 KB pad)
  float* h1f   = (float*)(ws + 1048576 + 4096);          // 256*512*4 = 524,288 B

  // zero h buffers (h[-1]=h[-2]=0) + flag words every call (graph-replay safe)
  hipMemsetAsync(d_ws, 0, 1048576 + 4096, stream);

  hipLaunchKernelGGL(lstm_persist, dim3(256), dim3(256), 0, stream,
                     x, Wih0, Whh0, bih0, bhh0, Wih1, Whh1, bih1, bhh1,
                     h0b, h1b, h1f, flags);
  hipLaunchKernelGGL(head_k, dim3(1), dim3(256), 0, stream,
                     h1f, Wlin, blin, y, (float*)d_out);
}